// Round 5
// baseline (741.312 us; speedup 1.0000x reference)
//
#include <hip/hip_runtime.h>

#define DEV __device__ __forceinline__

typedef unsigned short u16;
typedef unsigned int u32;
typedef __attribute__((ext_vector_type(4))) float f32x4;
typedef __attribute__((ext_vector_type(8))) short s16x8;
typedef __attribute__((ext_vector_type(8))) __bf16 bf16x8;

// Problem: B=4, N=4096, D=1024, H=16, HD=64, M=256. BH=64, BN=16384.
// ws budget ~68 MiB; kh/vT live in d_out (64 MiB) until the final GEMM.

DEV u16 f2bf(float f) {
  u32 u = __float_as_uint(f);
  u32 r = (u + 0x7FFFu + ((u >> 16) & 1u)) >> 16;
  return (u16)r;
}

DEV s16x8 pack8(float4 a, float4 b) {
  s16x8 r;
  r[0] = (short)f2bf(a.x); r[1] = (short)f2bf(a.y);
  r[2] = (short)f2bf(a.z); r[3] = (short)f2bf(a.w);
  r[4] = (short)f2bf(b.x); r[5] = (short)f2bf(b.y);
  r[6] = (short)f2bf(b.z); r[7] = (short)f2bf(b.w);
  return r;
}

DEV f32x4 mfma16(s16x8 a, s16x8 b, f32x4 c) {
  return __builtin_amdgcn_mfma_f32_16x16x32_bf16(
      __builtin_bit_cast(bf16x8, a), __builtin_bit_cast(bf16x8, b), c, 0, 0, 0);
}

DEV void gll16(const u16* g, u16* l) {
  __builtin_amdgcn_global_load_lds(
      (const __attribute__((address_space(1))) u32*)g,
      (__attribute__((address_space(3))) u32*)l, 16, 0, 0);
}

// ---------------- proj convert (16384 elems, pre-scaled by HD^-1/4) ------------
__global__ __launch_bounds__(256) void cvt_kernel(const float* __restrict__ s,
                                                  u16* __restrict__ d, int n, float scale) {
  int i = (blockIdx.x * 256 + threadIdx.x) * 8;
  if (i >= n) return;
  float4 a = *(const float4*)(s + i);
  float4 b = *(const float4*)(s + i + 4);
  s16x8 r;
  r[0] = (short)f2bf(a.x * scale); r[1] = (short)f2bf(a.y * scale);
  r[2] = (short)f2bf(a.z * scale); r[3] = (short)f2bf(a.w * scale);
  r[4] = (short)f2bf(b.x * scale); r[5] = (short)f2bf(b.y * scale);
  r[6] = (short)f2bf(b.z * scale); r[7] = (short)f2bf(b.w * scale);
  *(s16x8*)(d + i) = r;
}

// ---------------- QKV GEMM, fp32 inputs, reg-staged convert to LDS ----------------
// C[i][j] = sum_d A[i][d]*Bw[j][d] + bias[j]. I=16384, J=1024, K=1024.
// 128x128 tile, 4 waves (2x2 of 64x64), BK=32.
// EPI 1: split-head bf16 xh[(b*16+h)*4096+n][hd] + diag f32 (sum x^2/16)
// EPI 2: transposed bf16 vT[((b*16+h)*64+hd)*4096 + n]
template <int EPI>
__global__ __launch_bounds__(256) void gemm_rs(const float* __restrict__ A,
                                               const float* __restrict__ Bw,
                                               const float* __restrict__ bias,
                                               u16* __restrict__ obf,
                                               float* __restrict__ of32) {
  __shared__ u16 As[128 * 32];
  __shared__ u16 Bs[128 * 32];
  const int t = threadIdx.x;
  const int w = t >> 6, L = t & 63;
  const int wr = w >> 1, wc = w & 1;
  const int fr = L & 15, fq = L >> 4;
  const int i0 = blockIdx.x * 128, j0 = blockIdx.y * 128;

  const int row = t >> 1, ch = (t & 1) * 16;  // 2 threads/row, 16 f32 each
  const float* gA = A + (size_t)(i0 + row) * 1024 + ch;
  const float* gB = Bw + (size_t)(j0 + row) * 1024 + ch;

  f32x4 acc[4][4] = {};

  for (int kk = 0; kk < 1024; kk += 32) {
    float4 a0 = *(const float4*)(gA + kk);
    float4 a1 = *(const float4*)(gA + kk + 4);
    float4 a2 = *(const float4*)(gA + kk + 8);
    float4 a3 = *(const float4*)(gA + kk + 12);
    float4 b0 = *(const float4*)(gB + kk);
    float4 b1 = *(const float4*)(gB + kk + 4);
    float4 b2 = *(const float4*)(gB + kk + 8);
    float4 b3 = *(const float4*)(gB + kk + 12);
    __syncthreads();  // prior iter's fragment reads complete
    *(s16x8*)(As + row * 32 + ch) = pack8(a0, a1);
    *(s16x8*)(As + row * 32 + ch + 8) = pack8(a2, a3);
    *(s16x8*)(Bs + row * 32 + ch) = pack8(b0, b1);
    *(s16x8*)(Bs + row * 32 + ch + 8) = pack8(b2, b3);
    __syncthreads();
    s16x8 av[4], bv[4];
#pragma unroll
    for (int mi = 0; mi < 4; ++mi)
      av[mi] = *(const s16x8*)(As + (wr * 64 + mi * 16 + fr) * 32 + fq * 8);
#pragma unroll
    for (int nj = 0; nj < 4; ++nj)
      bv[nj] = *(const s16x8*)(Bs + (wc * 64 + nj * 16 + fr) * 32 + fq * 8);
#pragma unroll
    for (int mi = 0; mi < 4; ++mi)
#pragma unroll
      for (int nj = 0; nj < 4; ++nj)
        acc[mi][nj] = mfma16(av[mi], bv[nj], acc[mi][nj]);
  }

  float bj[4];
#pragma unroll
  for (int nj = 0; nj < 4; ++nj) bj[nj] = bias[j0 + wc * 64 + nj * 16 + fr];

  if (EPI == 1) {
    const int hcol = (j0 + wc * 64) >> 6;
#pragma unroll
    for (int mi = 0; mi < 4; ++mi) {
      float ss[4] = {0.f, 0.f, 0.f, 0.f};
#pragma unroll
      for (int nj = 0; nj < 4; ++nj)
#pragma unroll
        for (int r = 0; r < 4; ++r) {
          int i = i0 + wr * 64 + mi * 16 + fq * 4 + r;
          int bb = i >> 12, n = i & 4095;
          float v = acc[mi][nj][r] + bj[nj];
          obf[(((size_t)(bb * 16 + hcol) * 4096 + n) << 6) + nj * 16 + fr] = f2bf(v);
          ss[r] += v * v;
        }
#pragma unroll
      for (int r = 0; r < 4; ++r) {
        float s = ss[r];
        s += __shfl_xor(s, 1); s += __shfl_xor(s, 2);
        s += __shfl_xor(s, 4); s += __shfl_xor(s, 8);
        if (fr == 0) {
          int i = i0 + wr * 64 + mi * 16 + fq * 4 + r;
          int bb = i >> 12, n = i & 4095;
          of32[(size_t)(bb * 16 + hcol) * 4096 + n] = s * 0.0625f;
        }
      }
    }
  } else {
    const int hcol = (j0 + wc * 64) >> 6;
#pragma unroll
    for (int mi = 0; mi < 4; ++mi)
#pragma unroll
      for (int nj = 0; nj < 4; ++nj)
#pragma unroll
        for (int rp = 0; rp < 2; ++rp) {
          int i = i0 + wr * 64 + mi * 16 + fq * 4 + rp * 2;
          int bb = i >> 12, n = i & 4095;
          float v0 = acc[mi][nj][rp * 2] + bj[nj];
          float v1 = acc[mi][nj][rp * 2 + 1] + bj[nj];
          u32 pk = (u32)f2bf(v0) | ((u32)f2bf(v1) << 16);
          *(u32*)(obf + (((size_t)(bb * 16 + hcol) * 64 + nj * 16 + fr) * 4096 + n)) = pk;
        }
  }
}

// ---------------- final GEMM: attn(bf16) . Wo(f32)^T + bo -> f32 out ----------------
__global__ __launch_bounds__(256) void gemm_fin(const u16* __restrict__ A,
                                                const float* __restrict__ Bw,
                                                const float* __restrict__ bias,
                                                float* __restrict__ of32) {
  __shared__ u16 As[128 * 32];
  __shared__ u16 Bs[128 * 32];
  const int t = threadIdx.x;
  const int w = t >> 6, L = t & 63;
  const int wr = w >> 1, wc = w & 1;
  const int fr = L & 15, fq = L >> 4;
  const int i0 = blockIdx.x * 128, j0 = blockIdx.y * 128;

  const int srow = t >> 2, scol = (t & 3) * 8;
  const u16* ga0 = A + (size_t)(i0 + srow) * 1024 + scol;
  const u16* ga1 = ga0 + (size_t)64 * 1024;
  u16* la0 = As + w * 512;
  u16* la1 = As + 2048 + w * 512;

  const int row = t >> 1, ch = (t & 1) * 16;
  const float* gB = Bw + (size_t)(j0 + row) * 1024 + ch;

  f32x4 acc[4][4] = {};

  for (int kk = 0; kk < 1024; kk += 32) {
    float4 b0 = *(const float4*)(gB + kk);
    float4 b1 = *(const float4*)(gB + kk + 4);
    float4 b2 = *(const float4*)(gB + kk + 8);
    float4 b3 = *(const float4*)(gB + kk + 12);
    __syncthreads();  // prior fragment reads complete
    *(s16x8*)(Bs + row * 32 + ch) = pack8(b0, b1);
    *(s16x8*)(Bs + row * 32 + ch + 8) = pack8(b2, b3);
    gll16(ga0 + kk, la0);  // issued after barrier -> lands after prior reads
    gll16(ga1 + kk, la1);
    __syncthreads();  // drains vmcnt (gll) + lgkmcnt (ds_write)
    s16x8 av[4], bv[4];
#pragma unroll
    for (int mi = 0; mi < 4; ++mi)
      av[mi] = *(const s16x8*)(As + (wr * 64 + mi * 16 + fr) * 32 + fq * 8);
#pragma unroll
    for (int nj = 0; nj < 4; ++nj)
      bv[nj] = *(const s16x8*)(Bs + (wc * 64 + nj * 16 + fr) * 32 + fq * 8);
#pragma unroll
    for (int mi = 0; mi < 4; ++mi)
#pragma unroll
      for (int nj = 0; nj < 4; ++nj)
        acc[mi][nj] = mfma16(av[mi], bv[nj], acc[mi][nj]);
  }

  float bj[4];
#pragma unroll
  for (int nj = 0; nj < 4; ++nj) bj[nj] = bias[j0 + wc * 64 + nj * 16 + fr];
#pragma unroll
  for (int mi = 0; mi < 4; ++mi)
#pragma unroll
    for (int nj = 0; nj < 4; ++nj)
#pragma unroll
      for (int r = 0; r < 4; ++r) {
        int i = i0 + wr * 64 + mi * 16 + fq * 4 + r;
        int j = j0 + wc * 64 + nj * 16 + fr;
        of32[(size_t)i * 1024 + j] = acc[mi][nj][r] + bj[nj];
      }
}

// ---------------- fused feat-K + KV partial ----------------
// grid: 64 bh x 8 splits; 8 n-subblocks of 64 rows each.
// k' = exp(proj.xk^T - diag)/16 in LDS, KVt_part[d][m] += vT_tile . k'T.
__global__ __launch_bounds__(256) void featkv_kernel(const u16* __restrict__ kh,
                                                     const u16* __restrict__ vT,
                                                     const u16* __restrict__ pjS,
                                                     const float* __restrict__ diag,
                                                     float* __restrict__ part,
                                                     float* __restrict__ ksum) {
  __shared__ u16 xS[64 * 72];
  __shared__ u16 vS[64 * 72];
  __shared__ u16 tb[256 * 72];
  __shared__ float dS[64];
  const int t = threadIdx.x, w = t >> 6, L = t & 63;
  const int fr = L & 15, fq = L >> 4;
  const int bh = blockIdx.x >> 3, sp = blockIdx.x & 7;

  s16x8 av[4][2];
#pragma unroll
  for (int fi = 0; fi < 4; ++fi)
#pragma unroll
    for (int ks = 0; ks < 2; ++ks)
      av[fi][ks] = *(const s16x8*)(pjS + (size_t)(w * 64 + fi * 16 + fr) * 64 + ks * 32 + fq * 8);

  f32x4 akv[4][4] = {};
  float ksr[4][4] = {{0.f}};

  for (int it = 0; it < 8; ++it) {
    const int n0 = (sp * 8 + it) * 64;
#pragma unroll
    for (int i2 = 0; i2 < 2; ++i2) {
      int c = t + i2 * 256;
      int row = c >> 3, c8 = (c & 7) * 8;
      *(s16x8*)(xS + row * 72 + c8) =
          *(const s16x8*)(kh + ((size_t)bh * 4096 + n0 + row) * 64 + c8);
      *(s16x8*)(vS + row * 72 + c8) =
          *(const s16x8*)(vT + ((size_t)bh * 64 + row) * 4096 + n0 + c8);
    }
    if (t < 64) dS[t] = diag[(size_t)bh * 4096 + n0 + t];
    __syncthreads();

    f32x4 as_[4][4] = {};
#pragma unroll
    for (int ks = 0; ks < 2; ++ks) {
      s16x8 bv[4];
#pragma unroll
      for (int fj = 0; fj < 4; ++fj)
        bv[fj] = *(const s16x8*)(xS + (fj * 16 + fr) * 72 + ks * 32 + fq * 8);
#pragma unroll
      for (int fi = 0; fi < 4; ++fi)
#pragma unroll
        for (int fj = 0; fj < 4; ++fj)
          as_[fi][fj] = mfma16(av[fi][ks], bv[fj], as_[fi][fj]);
    }
    float dv[4];
#pragma unroll
    for (int fj = 0; fj < 4; ++fj) dv[fj] = dS[fj * 16 + fr];
#pragma unroll
    for (int fi = 0; fi < 4; ++fi)
#pragma unroll
      for (int fj = 0; fj < 4; ++fj)
#pragma unroll
        for (int r = 0; r < 4; ++r)
          as_[fi][fj][r] = __expf(as_[fi][fj][r] - dv[fj]) * 0.0625f;
#pragma unroll
    for (int fi = 0; fi < 4; ++fi)
#pragma unroll
      for (int r = 0; r < 4; ++r) {
        float s = as_[fi][0][r] + as_[fi][1][r] + as_[fi][2][r] + as_[fi][3][r];
        s += __shfl_xor(s, 1); s += __shfl_xor(s, 2);
        s += __shfl_xor(s, 4); s += __shfl_xor(s, 8);
        ksr[fi][r] += s;
      }
#pragma unroll
    for (int fi = 0; fi < 4; ++fi)
#pragma unroll
      for (int fj = 0; fj < 4; ++fj)
#pragma unroll
        for (int r = 0; r < 4; ++r)
          tb[(size_t)(w * 64 + fi * 16 + fq * 4 + r) * 72 + fj * 16 + fr] =
              f2bf(as_[fi][fj][r]);
    __syncthreads();

#pragma unroll
    for (int ks2 = 0; ks2 < 2; ++ks2) {
      s16x8 avv[4], bvv[4];
#pragma unroll
      for (int fi2 = 0; fi2 < 4; ++fi2)
        avv[fi2] = *(const s16x8*)(vS + (fi2 * 16 + fr) * 72 + ks2 * 32 + fq * 8);
#pragma unroll
      for (int fj2 = 0; fj2 < 4; ++fj2)
        bvv[fj2] = *(const s16x8*)(tb + (w * 64 + fj2 * 16 + fr) * 72 + ks2 * 32 + fq * 8);
#pragma unroll
      for (int fi2 = 0; fi2 < 4; ++fi2)
#pragma unroll
        for (int fj2 = 0; fj2 < 4; ++fj2)
          akv[fi2][fj2] = mfma16(avv[fi2], bvv[fj2], akv[fi2][fj2]);
    }
    __syncthreads();
  }

  float* pp = part + ((size_t)(sp * 64 + bh)) * 16384;
#pragma unroll
  for (int fi2 = 0; fi2 < 4; ++fi2)
#pragma unroll
    for (int fj2 = 0; fj2 < 4; ++fj2)
#pragma unroll
      for (int r = 0; r < 4; ++r)
        pp[(size_t)(fi2 * 16 + fq * 4 + r) * 256 + w * 64 + fj2 * 16 + fr] =
            akv[fi2][fj2][r];
  if (fr == 0) {
#pragma unroll
    for (int fi = 0; fi < 4; ++fi)
#pragma unroll
      for (int r = 0; r < 4; ++r)
        atomicAdd(&ksum[bh * 256 + w * 64 + fi * 16 + fq * 4 + r], ksr[fi][r]);
  }
}

// ---------------- reduce split-K partials -> kvt bf16 [bh][64][256] ----------------
__global__ __launch_bounds__(256) void kvred_kernel(const float* __restrict__ part,
                                                    u16* __restrict__ kvt) {
  int gid = blockIdx.x * 256 + threadIdx.x;
#pragma unroll
  for (int l = 0; l < 4; ++l) {
    int i = gid + l * 262144;
    int bh = i >> 14, j = i & 16383;
    float v = 0.f;
#pragma unroll
    for (int s = 0; s < 8; ++s) v += part[((size_t)(s * 64 + bh) << 14) + j];
    kvt[i] = f2bf(v);
  }
}

// ---------------- fused feat-Q + out ----------------
__global__ __launch_bounds__(256) void featout_kernel(const u16* __restrict__ qh,
                                                      const u16* __restrict__ pjS,
                                                      const float* __restrict__ diag,
                                                      const u16* __restrict__ kvt,
                                                      const float* __restrict__ ksum,
                                                      u16* __restrict__ attn) {
  __shared__ u16 uS[21120];   // phase1: xS[128][72]; phase2: bS[80][264]
  __shared__ u16 tb[64 * 264];
  __shared__ float mxS[2][128];
  __shared__ float dS[128];
  const int t = threadIdx.x, w = t >> 6, L = t & 63;
  const int wr = w >> 1, wc = w & 1;
  const int fr = L & 15, fq = L >> 4;
  const int bh = blockIdx.x >> 5;
  const int n0 = (blockIdx.x & 31) << 7;

  const u16* xg = qh + ((size_t)bh * 4096 + n0) * 64;
#pragma unroll
  for (int i2 = 0; i2 < 4; ++i2) {
    int c = t + i2 * 256;
    int row = c >> 3, c8 = (c & 7) * 8;
    *(s16x8*)(uS + row * 72 + c8) = *(const s16x8*)(xg + (size_t)row * 64 + c8);
  }
  if (t < 128) dS[t] = diag[(size_t)bh * 4096 + n0 + t];

  s16x8 av[8][2];
#pragma unroll
  for (int fi = 0; fi < 8; ++fi)
#pragma unroll
    for (int ks = 0; ks < 2; ++ks)
      av[fi][ks] = *(const s16x8*)(pjS + (size_t)(wr * 128 + fi * 16 + fr) * 64 + ks * 32 + fq * 8);
  __syncthreads();

  f32x4 acc[8][4] = {};
#pragma unroll
  for (int ks = 0; ks < 2; ++ks) {
    s16x8 bv[4];
#pragma unroll
    for (int fj = 0; fj < 4; ++fj)
      bv[fj] = *(const s16x8*)(uS + (wc * 64 + fj * 16 + fr) * 72 + ks * 32 + fq * 8);
#pragma unroll
    for (int fi = 0; fi < 8; ++fi)
#pragma unroll
      for (int fj = 0; fj < 4; ++fj)
        acc[fi][fj] = mfma16(av[fi][ks], bv[fj], acc[fi][fj]);
  }

  float dv[4];
#pragma unroll
  for (int fj = 0; fj < 4; ++fj) dv[fj] = dS[wc * 64 + fj * 16 + fr];

  float mx[4];
#pragma unroll
  for (int fj = 0; fj < 4; ++fj) {
    float m = -3.4e38f;
#pragma unroll
    for (int fi = 0; fi < 8; ++fi)
#pragma unroll
      for (int r = 0; r < 4; ++r) m = fmaxf(m, acc[fi][fj][r]);
    m = fmaxf(m, __shfl_xor(m, 16));
    m = fmaxf(m, __shfl_xor(m, 32));
    mx[fj] = m;
  }
  if (L < 16) {
#pragma unroll
    for (int fj = 0; fj < 4; ++fj) mxS[wr][wc * 64 + fj * 16 + L] = mx[fj];
  }
  __syncthreads();  // mxS ready; all uS(xS) reads done
#pragma unroll
  for (int fj = 0; fj < 4; ++fj) {
    int n = wc * 64 + fj * 16 + fr;
    mx[fj] = fmaxf(mxS[0][n], mxS[1][n]);
  }

  // stage Bext into uS: rows 0..63 = KVt[d][m], row 64 = ksum, rows 65..79 = 0
  const u16* kv = kvt + (size_t)bh * 16384;
#pragma unroll
  for (int i2 = 0; i2 < 8; ++i2) {
    int c = t + i2 * 256;
    int row = c >> 5, c8 = (c & 31) * 8;
    *(s16x8*)(uS + row * 264 + c8) = *(const s16x8*)(kv + (size_t)row * 256 + c8);
  }
  uS[64 * 264 + t] = f2bf(ksum[bh * 256 + t]);
#pragma unroll
  for (int i2 = 0; i2 < 16; ++i2) {
    int c = t + i2 * 256;
    if (c < 15 * 264) uS[65 * 264 + c] = 0;
  }

  const int b_ = bh >> 4, h = bh & 15;
  for (int pass = 0; pass < 2; ++pass) {
    __syncthreads();
    if (wc == pass) {
#pragma unroll
      for (int fi = 0; fi < 8; ++fi)
#pragma unroll
        for (int fj = 0; fj < 4; ++fj) {
          int n = fj * 16 + fr;
          int m = wr * 128 + fi * 16 + fq * 4;
          float e0 = __expf(acc[fi][fj][0] - mx[fj] - dv[fj]) * 0.0625f;
          float e1 = __expf(acc[fi][fj][1] - mx[fj] - dv[fj]) * 0.0625f;
          float e2 = __expf(acc[fi][fj][2] - mx[fj] - dv[fj]) * 0.0625f;
          float e3 = __expf(acc[fi][fj][3] - mx[fj] - dv[fj]) * 0.0625f;
          u32* p = (u32*)(tb + (size_t)n * 264 + m);
          p[0] = (u32)f2bf(e0) | ((u32)f2bf(e1) << 16);
          p[1] = (u32)f2bf(e2) | ((u32)f2bf(e3) << 16);
        }
    }
    __syncthreads();
    f32x4 ao[5] = {};
    for (int ks = 0; ks < 8; ++ks) {
      s16x8 a = *(const s16x8*)(tb + (size_t)(w * 16 + fr) * 264 + ks * 32 + fq * 8);
#pragma unroll
      for (int fj = 0; fj < 5; ++fj) {
        s16x8 bvv = *(const s16x8*)(uS + (size_t)(fj * 16 + fr) * 264 + ks * 32 + fq * 8);
        ao[fj] = mfma16(a, bvv, ao[fj]);
      }
    }
#pragma unroll
    for (int r = 0; r < 4; ++r) {
      float nv = __shfl(ao[4][r], (int)(L & 48), 64);
      nv = fmaxf(nv, 1e-6f);
      float ri = 1.0f / nv;
      int n = n0 + pass * 64 + w * 16 + fq * 4 + r;
#pragma unroll
      for (int fj = 0; fj < 4; ++fj)
        attn[((size_t)b_ * 4096 + n) * 1024 + h * 64 + fj * 16 + fr] =
            f2bf(ao[fj][r] * ri);
    }
  }
}

// ---------------- launcher ----------------
extern "C" void kernel_launch(void* const* d_in, const int* in_sizes, int n_in,
                              void* d_out, int out_size, void* d_ws, size_t ws_size,
                              hipStream_t stream) {
  const float* q = (const float*)d_in[0];
  const float* k = (const float*)d_in[1];
  const float* v = (const float*)d_in[2];
  const float* Wq = (const float*)d_in[3];
  const float* bq = (const float*)d_in[4];
  const float* Wk = (const float*)d_in[5];
  const float* bk = (const float*)d_in[6];
  const float* Wv = (const float*)d_in[7];
  const float* bv = (const float*)d_in[8];
  const float* Wo = (const float*)d_in[9];
  const float* bo = (const float*)d_in[10];
  const float* proj = (const float*)d_in[11];

  char* ws = (char*)d_ws;
  size_t off = 0;
  auto alloc = [&](size_t bytes) {
    char* p = ws + off;
    off += (bytes + 255) & ~(size_t)255;
    return p;
  };

  u16* pjS = (u16*)alloc((size_t)16384 * 2);         // 32 KiB
  u16* qh = (u16*)alloc((size_t)16777216 * 2);       // 32 MiB
  float* dq = (float*)alloc((size_t)262144 * 4);     // 1 MiB
  float* dk = (float*)alloc((size_t)262144 * 4);     // 1 MiB
  float* ks_ = (float*)alloc((size_t)64 * 256 * 4);  // 64 KiB
  u16* kvt = (u16*)alloc((size_t)64 * 16384 * 2);    // 2 MiB
  char* reg = alloc((size_t)33554432);               // 32 MiB (part, then attn)
  size_t needed = off;
  if (ws_size < needed) return;  // diagnostic: ws too small -> poisoned out, no crash

  float* part = (float*)reg;     // featkv partials (dies at kvred)
  u16* attn = (u16*)reg;         // featout output (born after part dies)

  // kh/vT live inside d_out until gemm_fin overwrites it
  u16* kh = (u16*)d_out;                  // 32 MiB
  u16* vT = (u16*)d_out + 16777216;       // 32 MiB

  cvt_kernel<<<8, 256, 0, stream>>>(proj, pjS, 16384, 0.35355339059327373f);

  dim3 g1(128, 8);
  gemm_rs<1><<<g1, 256, 0, stream>>>(q, Wq, bq, qh, dq);
  gemm_rs<1><<<g1, 256, 0, stream>>>(k, Wk, bk, kh, dk);
  gemm_rs<2><<<g1, 256, 0, stream>>>(v, Wv, bv, vT, nullptr);

  hipMemsetAsync(ks_, 0, (size_t)64 * 256 * 4, stream);

  featkv_kernel<<<512, 256, 0, stream>>>(kh, vT, pjS, dk, part, ks_);
  kvred_kernel<<<1024, 256, 0, stream>>>(part, kvt);
  featout_kernel<<<2048, 256, 0, stream>>>(qh, pjS, dq, kvt, ks_, attn);

  gemm_fin<<<g1, 256, 0, stream>>>(attn, Wo, bo, (float*)d_out);

  (void)in_sizes; (void)n_in; (void)out_size;
}